// Round 1
// baseline (170.956 us; speedup 1.0000x reference)
//
#include <hip/hip_runtime.h>
#include <hip/hip_cooperative_groups.h>

namespace cg = cooperative_groups;

// Problem constants (fixed by reference)
#define GS    256
#define PARAM 128
#define KC    32
#define I1    64
#define I2    32
#define PK    96        // PARAM - KC
#define B_    4
#define NROWS (B_ * GS) // 1024
#define EPS   1e-3f
#define KDIV_INV (1.0f / 16.0f)

// Workspace layout (float offsets) — only U and W now (folding is inline)
constexpr int U_OFF = 0;            // NROWS*I1
constexpr int W_OFF = NROWS * I1;   // NROWS*I1

__device__ __forceinline__ float rdlane(float v, int l) {
    return __uint_as_float(__builtin_amdgcn_readlane(__float_as_uint(v), l));
}

// Fused kernel. phase==0: both phases + grid.sync (cooperative launch).
// phase==1 / phase==2: fallback split launches (no grid sync executed).
//
// Phase 1 (per row r): u = val.(M1top - M1bot), W = val.M1bot, both *s1,
//   via 4 quarter-dots (wave q owns quarter q). Also copies con = val[:, :KC].
// Phase 2 (per row r): compact mask row, then per active pair run the MLP
//   entirely in registers with v_readlane broadcasts (wave-uniform index ->
//   SGPR operand of v_fma). Weights are folded inline from raw M2/M3/g/v
//   into per-lane registers ONCE per block (row-independent, hoisted out of
//   the persistent row loop).
__global__ __launch_bounds__(256, 3) void glmlp_fused(
    const float* __restrict__ mat, const float* __restrict__ val,
    const float* __restrict__ M1, const float* __restrict__ B1,
    const float* __restrict__ M2, const float* __restrict__ B2,
    const float* __restrict__ M3, const float* __restrict__ B3,
    const float* __restrict__ g1, const float* __restrict__ b1,
    const float* __restrict__ m1, const float* __restrict__ v1,
    const float* __restrict__ g2, const float* __restrict__ b2,
    const float* __restrict__ m2, const float* __restrict__ v2,
    const float* __restrict__ g3, const float* __restrict__ b3,
    const float* __restrict__ m3, const float* __restrict__ v3,
    float* __restrict__ ws, float* __restrict__ out, int phase)
{
    __shared__ float vrow[PARAM];       // 512 B
    __shared__ float red[4][I1];        // 1 KB
    __shared__ int   acty[GS];          // 1 KB
    __shared__ float partial[4][PK];    // 1.5 KB
    __shared__ int   cnt;

    const int nb   = gridDim.x;
    const int t    = threadIdx.x;
    const int lane = t & 63;
    const int w    = t >> 6;            // wave id 0..3
    const int jj   = lane & 31;

    // ---------------- Phase 1 ----------------
    if (phase != 2) {
        for (int r = blockIdx.x; r < NROWS; r += nb) {
            if (t < PARAM) vrow[t] = val[r * PARAM + t];
            if (t < KC)    out[r * PARAM + t] = val[r * PARAM + t];
            __syncthreads();

            const int i = lane;
            const int q = w;                              // 0..3
            // q=0,1 -> T (M1 top half); q=2,3 -> W (M1 bottom half)
            const float* __restrict__ Mb = M1 + ((q >> 1) ? (PARAM * I1) : 0);
            const int p0 = (q & 1) * 64;
            float aa = 0.f, bb = 0.f;                     // dual chains
            #pragma unroll 8
            for (int p = 0; p < 64; p += 2) {
                aa = fmaf(vrow[p0 + p],     Mb[(p0 + p) * I1 + i],     aa);
                bb = fmaf(vrow[p0 + p + 1], Mb[(p0 + p + 1) * I1 + i], bb);
            }
            red[q][i] = aa + bb;
            __syncthreads();

            if (q == 0) {
                const float T  = red[0][i] + red[1][i];
                const float Wv = red[2][i] + red[3][i];
                const float s1 = g1[i] * rsqrtf(v1[i] + EPS);
                ws[U_OFF + r * I1 + i] = (T - Wv) * s1;
                ws[W_OFF + r * I1 + i] = Wv * s1;
            }
            // next-iteration start barrier protects vrow/red reuse
        }
    }

    if (phase == 0) cg::this_grid().sync();

    // ---------------- Phase 2 ----------------
    if (phase != 1) {
        // Inline BN folding into register-resident weights (row-independent).
        // lane (h=lane>>5, jj=lane&31):
        //   m2col[s] = M2f[s][jj]      (full column, dup across halves)
        //   m3a[i]   = M3f[i][lane]    (k = lane)
        //   m3b[i]   = M3f[i][64+jj]   (k = 64+jj, dup across halves)
        const float s2  = g2[jj] * rsqrtf(v2[jj] + EPS);
        float m2col[I1];                    // 64 VGPR
        #pragma unroll
        for (int s = 0; s < I1; ++s)
            m2col[s] = M2[s * I2 + jj] * s2;

        const float s3a = g3[lane]    * rsqrtf(v3[lane]    + EPS);
        const float s3b = g3[64 + jj] * rsqrtf(v3[64 + jj] + EPS);
        float m3a[I2], m3b[I2];             // 64 VGPR
        #pragma unroll
        for (int k = 0; k < I2; ++k) {
            m3a[k] = M3[k * PK + lane]    * s3a;
            m3b[k] = M3[k * PK + 64 + jj] * s3b;
        }

        const float s1l = g1[lane] * rsqrtf(v1[lane] + EPS);
        const float c1l = B1[lane] * s1l + b1[lane] - m1[lane] * s1l;
        const float c2j = B2[jj]   * s2  + b2[jj]   - m2[jj]   * s2;
        const float c30 = B3[lane]    * s3a + b3[lane]    - m3[lane]    * s3a;
        const float c31 = B3[64 + jj] * s3b + b3[64 + jj] - m3[64 + jj] * s3b;

        const float* __restrict__ W = ws + W_OFF;

        for (int r = blockIdx.x; r < NROWS; r += nb) {
            const int wbase = r & ~(GS - 1);    // b * GS
            if (t == 0) cnt = 0;
            __syncthreads();                    // cnt=0 visible; guards acty reuse
            const float mv = mat[r * GS + t];
            if (mv != 0.0f) acty[atomicAdd(&cnt, 1)] = t;   // values are exactly 0/1
            const float ux = ws[U_OFF + r * I1 + lane] + c1l;
            __syncthreads();
            const int n = cnt;

            float acc0 = 0.f, acc1 = 0.f;

            int p = w;
            float wv = (p < n) ? W[(wbase + acty[p]) * I1 + lane] : 0.f;
            while (p < n) {
                const int pn = p + 4;
                const float wvn = (pn < n) ? W[(wbase + acty[pn]) * I1 + lane] : 0.f;

                // Layer 1 (register): lane holds H1[lane]
                const float h1 = fmaxf(ux + wv, 0.f);

                // Layer 2: full dot for column jj via 64 uniform readlane
                // broadcasts; 4 interleaved chains (dep 16).
                float a0 = 0.f, a1 = 0.f, a2 = 0.f, a3 = 0.f;
                #pragma unroll
                for (int s = 0; s < I1; s += 4) {
                    a0 = fmaf(rdlane(h1, s + 0), m2col[s + 0], a0);
                    a1 = fmaf(rdlane(h1, s + 1), m2col[s + 1], a1);
                    a2 = fmaf(rdlane(h1, s + 2), m2col[s + 2], a2);
                    a3 = fmaf(rdlane(h1, s + 3), m2col[s + 3], a3);
                }
                const float h2 = fmaxf((a0 + a1) + (a2 + a3) + c2j, 0.f);

                // Layer 3: 32 uniform broadcasts serve both output columns
                // k0 = lane, k1 = 64+jj. Dual chains each.
                float d0a = c30, d0b = 0.f, d1a = c31, d1b = 0.f;
                #pragma unroll
                for (int k = 0; k < I2; k += 2) {
                    const float he = rdlane(h2, k);
                    const float ho = rdlane(h2, k + 1);
                    d0a = fmaf(he, m3a[k],     d0a);
                    d0b = fmaf(ho, m3a[k + 1], d0b);
                    d1a = fmaf(he, m3b[k],     d1a);
                    d1b = fmaf(ho, m3b[k + 1], d1b);
                }
                acc0 += fmaxf(d0a + d0b, 0.f);
                acc1 += fmaxf(d1a + d1b, 0.f);

                wv = wvn;
                p = pn;
            }

            partial[w][lane] = acc0;
            if (lane < 32) partial[w][64 + lane] = acc1;  // halves hold identical acc1
            __syncthreads();

            if (t < PK) {
                float v = (partial[0][t] + partial[1][t] +
                           partial[2][t] + partial[3][t]) * KDIV_INV;
                v = fminf(fmaxf(v, -1.0f), 1.0f);
                out[r * PARAM + KC + t] = v;
            }
            __syncthreads();                    // partial reuse across rows
        }
    }
}

extern "C" void kernel_launch(void* const* d_in, const int* in_sizes, int n_in,
                              void* d_out, int out_size, void* d_ws, size_t ws_size,
                              hipStream_t stream) {
    const float* mat = (const float*)d_in[0];
    const float* val = (const float*)d_in[1];
    const float* M1  = (const float*)d_in[2];
    const float* B1  = (const float*)d_in[3];
    const float* M2  = (const float*)d_in[4];
    const float* B2  = (const float*)d_in[5];
    const float* M3  = (const float*)d_in[6];
    const float* B3  = (const float*)d_in[7];
    const float* g1  = (const float*)d_in[8];
    const float* b1  = (const float*)d_in[9];
    const float* m1  = (const float*)d_in[10];
    const float* v1  = (const float*)d_in[11];
    const float* g2  = (const float*)d_in[12];
    const float* b2  = (const float*)d_in[13];
    const float* m2  = (const float*)d_in[14];
    const float* v2  = (const float*)d_in[15];
    const float* g3  = (const float*)d_in[16];
    const float* b3  = (const float*)d_in[17];
    const float* m3  = (const float*)d_in[18];
    const float* v3  = (const float*)d_in[19];

    float* ws  = (float*)d_ws;
    float* out = (float*)d_out;

    // Size the cooperative grid from actual occupancy (MI355X: 256 CUs) so
    // co-residency is guaranteed; persistent grid-stride covers all rows.
    int occ = 0;
    hipError_t qe = hipOccupancyMaxActiveBlocksPerMultiprocessor(
        &occ, (const void*)glmlp_fused, 256, 0);
    bool try_coop = (qe == hipSuccess) && (occ >= 1);
    int grid = 256 * (occ < 1 ? 1 : occ);
    if (grid > NROWS) grid = NROWS;

    hipError_t le = hipErrorUnknown;
    if (try_coop) {
        int phase0 = 0;
        void* args[] = {
            (void*)&mat, (void*)&val, (void*)&M1, (void*)&B1,
            (void*)&M2,  (void*)&B2,  (void*)&M3, (void*)&B3,
            (void*)&g1, (void*)&b1, (void*)&m1, (void*)&v1,
            (void*)&g2, (void*)&b2, (void*)&m2, (void*)&v2,
            (void*)&g3, (void*)&b3, (void*)&m3, (void*)&v3,
            (void*)&ws, (void*)&out, (void*)&phase0
        };
        le = hipLaunchCooperativeKernel((const void*)glmlp_fused,
                                        dim3(grid), dim3(256), args, 0, stream);
    }

    if (le != hipSuccess) {
        // Fallback: same kernel as two plain phase launches (old behavior).
        (void)hipGetLastError();
        hipLaunchKernelGGL(glmlp_fused, dim3(NROWS), dim3(256), 0, stream,
                           mat, val, M1, B1, M2, B2, M3, B3,
                           g1, b1, m1, v1, g2, b2, m2, v2, g3, b3, m3, v3,
                           ws, out, 1);
        hipLaunchKernelGGL(glmlp_fused, dim3(NROWS), dim3(256), 0, stream,
                           mat, val, M1, B1, M2, B2, M3, B3,
                           g1, b1, m1, v1, g2, b2, m2, v2, g3, b3, m3, v3,
                           ws, out, 2);
    }
}